// Round 1
// baseline (570.675 us; speedup 1.0000x reference)
//
#include <hip/hip_runtime.h>
#include <hip/hip_bf16.h>

// MLPPredictor: score[e, c] = bias[c] + sum_k concat(h[src[e]], h[dst[e]])[k] * W[c][k]
// N_NODES=100000, E=6.4M, D=5, C=16. fp32 in/out, int32 indices.
//
// Layout: thread g handles edge e = g>>2, class-quad q = g&3 (classes 4q..4q+3).
// Output elements g*4 .. g*4+3  ->  one float4 store, perfectly coalesced.
// W tile (4 rows x 10 + 4 bias = 44 fp32) lives in registers, loaded once per
// thread from LDS; grid-stride loop amortizes it (~24 edges-quads per thread).

constexpr int C = 16;        // out classes
constexpr int TWO_D = 10;    // 2 * D_FEAT

__global__ __launch_bounds__(256) void edge_mlp_kernel(
    const float* __restrict__ h,
    const int* __restrict__ src,
    const int* __restrict__ dst,
    const float* __restrict__ Ww,   // [C][2D] row-major
    const float* __restrict__ Wb,   // [C]
    float* __restrict__ out,        // [E][C]
    int totalItems)                 // E * 4
{
    __shared__ float sW[C * TWO_D + C];
    for (int i = threadIdx.x; i < C * TWO_D + C; i += blockDim.x) {
        sW[i] = (i < C * TWO_D) ? Ww[i] : Wb[i - C * TWO_D];
    }
    __syncthreads();

    const int tid0 = blockIdx.x * blockDim.x + threadIdx.x;
    const int q = tid0 & 3;   // class quad; invariant across grid-stride (stride % 4 == 0)

    // Register-resident W tile for my 4 classes.
    float w[4][TWO_D];
    float bias[4];
#pragma unroll
    for (int j = 0; j < 4; ++j) {
        const int c = q * 4 + j;
#pragma unroll
        for (int k = 0; k < TWO_D; ++k) w[j][k] = sW[c * TWO_D + k];
        bias[j] = sW[C * TWO_D + c];
    }

    const int stride = gridDim.x * blockDim.x;  // multiple of 4 (blockDim=256)
    for (int g = tid0; g < totalItems; g += stride) {
        const int e = g >> 2;
        const int s = src[e];
        const int d = dst[e];
        const float* pu = h + s * 5;
        const float* pv = h + d * 5;
        const float u0 = pu[0], u1 = pu[1], u2 = pu[2], u3 = pu[3], u4 = pu[4];
        const float v0 = pv[0], v1 = pv[1], v2 = pv[2], v3 = pv[3], v4 = pv[4];

        float4 r;
        float* rp = &r.x;
#pragma unroll
        for (int j = 0; j < 4; ++j) {
            float a = bias[j];
            a += u0 * w[j][0] + u1 * w[j][1] + u2 * w[j][2] + u3 * w[j][3] + u4 * w[j][4];
            a += v0 * w[j][5] + v1 * w[j][6] + v2 * w[j][7] + v3 * w[j][8] + v4 * w[j][9];
            rp[j] = a;
        }
        // out element index: e*16 + q*4 + j == g*4 + j  -> 16B-aligned float4 store
        *reinterpret_cast<float4*>(out + (size_t)g * 4) = r;
    }
}

extern "C" void kernel_launch(void* const* d_in, const int* in_sizes, int n_in,
                              void* d_out, int out_size, void* d_ws, size_t ws_size,
                              hipStream_t stream) {
    const float* h   = (const float*)d_in[0];   // [100000, 5]
    const int*   src = (const int*)d_in[1];     // [E]
    const int*   dst = (const int*)d_in[2];     // [E]
    const float* Ww  = (const float*)d_in[3];   // [16, 10]
    const float* Wb  = (const float*)d_in[4];   // [16]
    float* out = (float*)d_out;                 // [E, 16]

    const int E = in_sizes[1];
    const int totalItems = E * 4;               // 25.6M, fits int

    const int block = 256;
    const int grid = 4096;                       // persistent-ish grid-stride, ~24 items/thread

    edge_mlp_kernel<<<grid, block, 0, stream>>>(h, src, dst, Ww, Wb, out, totalItems);
}